// Round 1
// 88.419 us; speedup vs baseline: 1.0841x; 1.0841x over previous
//
#include <hip/hip_runtime.h>
#include <hip/hip_bf16.h>

#define NG 8192      // N_GRID
#define NB 64        // BATCH
#define CI 64        // C_IN
#define CO 64        // C_OUT
#define NM 64        // N_MODES
#define NFJ 128      // 2*N_MODES (re/im interleaved)
#define NROWS 4096   // BATCH*C_IN = BATCH*C_OUT

typedef __bf16 bf16x8 __attribute__((ext_vector_type(8)));
typedef float f32x4 __attribute__((ext_vector_type(4)));

#define GLOAD_LDS16(gsrc, ldst)                                                   \
    __builtin_amdgcn_global_load_lds(                                             \
        (const __attribute__((address_space(1))) void*)(gsrc),                    \
        (__attribute__((address_space(3))) void*)(ldst), 16, 0, 0)

// ---------------------------------------------------------------------------
// Workspace layout (offsets kept from prior version; XF region now unused):
//   [ 0, 2 MB)  __bf16 Ft_sw[128][8192]   fwd basis, 16B-group swizzle ^(j&7)
//   [ 2, 4 MB)  __bf16 Ginv_sw[8192][128] inv basis, 16B-group swizzle ^(n&15)
//   [ 6, 7 MB)  __bf16 M2[4096][128]
//   [ 7, 9 MB)  __bf16 Wtf  mix-weight MFMA B-fragments
//   [ 9, 9+split*2 MB)  float XFpT[split][128 j][4096 rows]   (TRANSPOSED)
// ---------------------------------------------------------------------------

// Fused: basis tables (blocks 0..8191) + weight pre-transpose (blocks 8192..8255)
__global__ __launch_bounds__(256) void sc_prep(const float* __restrict__ wr,
                                               const float* __restrict__ wi,
                                               __bf16* __restrict__ Ft,
                                               __bf16* __restrict__ Ginv,
                                               __bf16* __restrict__ Wtf) {
    const float W0 = 6.2831853071795864769f / (float)NG;
    if (blockIdx.x < 8192) {
        int idx = blockIdx.x * 256 + threadIdx.x;
        if (idx < 128 * NG) {            // Ft_sw
            int j = idx >> 13, pos = idx & (NG - 1);
            int blk = pos >> 6, g = (pos >> 3) & 7, e = pos & 7;
            int ksrc = (blk << 6) + (((g ^ (j & 7)) << 3) | e);
            int m = j >> 1;
            int t = (m * ksrc) & (NG - 1);
            float s, c;
            __sincosf((float)t * W0, &s, &c);
            Ft[idx] = (__bf16)((j & 1) ? -s : c);
        } else {                         // Ginv_sw
            int i2 = idx - 128 * NG;
            int n = i2 >> 7, pos = i2 & 127;
            int g = pos >> 3, e = pos & 7;
            int psrc = ((g ^ (n & 15)) << 3) | e;
            int m = psrc >> 1, im = psrc & 1;
            int t = (m * n) & (NG - 1);
            float s, c;
            __sincosf((float)t * W0, &s, &c);
            float v;
            if (im) v = (m == 0) ? 0.0f : (-2.0f / NG) * s;
            else    v = ((m == 0) ? 1.0f : 2.0f) / NG * c;
            Ginv[i2] = (__bf16)v;
        }
    } else {                             // Wtf fragments
        const int i = blockIdx.x - 8192, t = threadIdx.x;
        const int o = t & 63, kq = t >> 6;
        float wrk[16], wik[16];
        const float* pr = wr + ((size_t)i * 64 + o) * 64 + kq * 16;
        const float* pq = wi + ((size_t)i * 64 + o) * 64 + kq * 16;
        #pragma unroll
        for (int m = 0; m < 4; ++m) {
            float4 a = *(const float4*)(pr + m * 4);
            float4 b = *(const float4*)(pq + m * 4);
            wrk[m*4+0]=a.x; wrk[m*4+1]=a.y; wrk[m*4+2]=a.z; wrk[m*4+3]=a.w;
            wik[m*4+0]=b.x; wik[m*4+1]=b.y; wik[m*4+2]=b.z; wik[m*4+3]=b.w;
        }
        const int ks_a = i >> 5, ks_b = 2 + (i >> 5);
        const int kg = (i >> 3) & 3, e = i & 7, ot = o >> 4, l = o & 15;
        const int pos = (kg * 16 + l) * 8 + e;
        #pragma unroll
        for (int kk = 0; kk < 16; ++kk) {
            int k = kq * 16 + kk;
            Wtf[(size_t)(((k*2+0)*4+ks_a)*4+ot)*512 + pos] = (__bf16)wrk[kk];
            Wtf[(size_t)(((k*2+0)*4+ks_b)*4+ot)*512 + pos] = (__bf16)(-wik[kk]);
            Wtf[(size_t)(((k*2+1)*4+ks_a)*4+ot)*512 + pos] = (__bf16)wik[kk];
            Wtf[(size_t)(((k*2+1)*4+ks_b)*4+ot)*512 + pos] = (__bf16)wrk[kk];
        }
    }
}

// Kernel 1: split-K DFT GEMM. Block = 64 rows x 128 j x K-slice; 256 thr
// (waves 2x2). BK=64, double-buffered LDS, coalesced staging.
// Epilogue now writes TRANSPOSED partials XFpT[sp][j][row] so that
//  (a) each lane stores one f32x4 (4 consecutive rows), and lanes l15+16*kg
//      jointly fill a full 64B line of row j  -> perfectly coalesced;
//  (b) the mix kernel can read rows 2k,2k+1 as contiguous runs.
__global__ __launch_bounds__(256) void sc_dft(const float* __restrict__ A,
                                              const __bf16* __restrict__ Ft,
                                              float* __restrict__ XFp,
                                              int nsteps) {
    __shared__ __align__(16) char smem[49152];
    char* A0 = smem;            // 8 KB  [64 r][64 k] bf16, 16B-group swz ^(r&7)
    char* A1 = smem + 8192;
    char* F0 = smem + 16384;    // 16 KB [128 j][64 k] bf16, swz ^(j&7)
    char* F1 = smem + 32768;

    const int tid = threadIdx.x;
    const int w = tid >> 6, lane = tid & 63;
    const int l15 = lane & 15, kg = lane >> 4;
    const int wm = w >> 1, wn = w & 1;
    const int rt = blockIdx.x & 63, sp = blockIdx.x >> 6;
    const int r0 = rt * 64;
    const size_t kb0 = (size_t)sp * nsteps * 64;
    const int swz = l15 & 7;

    float4 av[4];
    f32x4 acc[2][4] = {};

    auto issueA = [&](int step) {
        size_t kb = kb0 + (size_t)step * 64;
        #pragma unroll
        for (int s = 0; s < 4; ++s) {
            int c = s * 256 + tid;
            av[s] = *(const float4*)(A + (size_t)(r0 + (c >> 4)) * NG + kb + (c & 15) * 4);
        }
    };
    auto writeA = [&](char* Ab) {
        #pragma unroll
        for (int s = 0; s < 4; ++s) {
            int c = s * 256 + tid, row = c >> 4, cq = c & 15;
            union { __bf16 h[4]; uint2 u; } cv;
            cv.h[0] = (__bf16)av[s].x; cv.h[1] = (__bf16)av[s].y;
            cv.h[2] = (__bf16)av[s].z; cv.h[3] = (__bf16)av[s].w;
            *(uint2*)(Ab + row * 128 + (((cq >> 1) ^ (row & 7)) << 4) + ((cq & 1) << 3)) = cv.u;
        }
    };
    auto stageF = [&](int step, char* Fb) {
        size_t kb = kb0 + (size_t)step * 64;
        #pragma unroll
        for (int s = 0; s < 4; ++s) {
            int cc = s * 256 + tid;
            GLOAD_LDS16(Ft + (size_t)(cc >> 3) * NG + kb + (cc & 7) * 8, Fb + cc * 16);
        }
    };
    auto compute = [&](const char* Ab, const char* Fb) {
        #pragma unroll
        for (int ks2 = 0; ks2 < 2; ++ks2) {
            bf16x8 a[2], b[4];
            #pragma unroll
            for (int mt = 0; mt < 2; ++mt)
                a[mt] = *(const bf16x8*)(Ab + (wm*32 + mt*16 + l15) * 128 +
                                         (((ks2*4 + kg) ^ swz) << 4));
            #pragma unroll
            for (int jt = 0; jt < 4; ++jt)
                b[jt] = *(const bf16x8*)(Fb + (wn*64 + jt*16 + l15) * 128 +
                                         (((ks2*4 + kg) ^ swz) << 4));
            #pragma unroll
            for (int mt = 0; mt < 2; ++mt)
                #pragma unroll
                for (int jt = 0; jt < 4; ++jt)
                    acc[mt][jt] = __builtin_amdgcn_mfma_f32_16x16x32_bf16(
                        a[mt], b[jt], acc[mt][jt], 0, 0, 0);
        }
    };

    issueA(0); stageF(0, F0); writeA(A0);
    __syncthreads();
    for (int t = 0; t < nsteps; ++t) {
        char* Ac = (t & 1) ? A1 : A0;
        char* Fc = (t & 1) ? F1 : F0;
        char* An = (t & 1) ? A0 : A1;
        char* Fn = (t & 1) ? F0 : F1;
        if (t + 1 < nsteps) { issueA(t + 1); stageF(t + 1, Fn); }
        compute(Ac, Fc);
        if (t + 1 < nsteps) writeA(An);
        __syncthreads();
    }
    // Transposed epilogue: XFpT[sp][j][row], f32x4 over 4 consecutive rows.
    #pragma unroll
    for (int mt = 0; mt < 2; ++mt)
        #pragma unroll
        for (int jt = 0; jt < 4; ++jt)
            *(f32x4*)(XFp + ((size_t)sp * NFJ + wn*64 + jt*16 + l15) * NROWS +
                      (r0 + wm*32 + mt*16 + kg*4)) = acc[mt][jt];
}

// Kernel 2: channel mix as per-mode MFMA GEMM [64b x 128(re|im)] x [128 x 64o].
// Split-K reduction FUSED into staging: reads rows 2k,2k+1 of XFpT (contiguous
// f32x4 runs per split), sums over splits in registers, packs to bf16x8 and
// writes one ds_write_b128 per thread into the swizzled LDS tile.
__global__ __launch_bounds__(256) void sc_mix(const float* __restrict__ XFp,
                                              const __bf16* __restrict__ Wtf,
                                              __bf16* __restrict__ M2, int nsplit) {
    __shared__ __align__(16) char at[4096];  // [16 b][128] bf16, 16B-grp swz ^b
    const int t = threadIdx.x;
    const int k = blockIdx.x >> 2, bq = blockIdx.x & 3;
    const int lane = t & 63, ot = t >> 6;
    const int l15 = lane & 15, kg = lane >> 4;

    // staging: thread t handles component c (re/im), rows t127*8 .. +7 of slab
    const int c = t >> 7, t127 = t & 127;
    f32x4 s0 = {}, s1 = {};
    {
        const float* src = XFp + (size_t)(2*k + c) * NROWS + bq*1024 + t127*8;
        const size_t pstride = (size_t)NFJ * NROWS;
        if (nsplit == 8) {
            #pragma unroll
            for (int p = 0; p < 8; ++p) {
                s0 += *(const f32x4*)(src + p*pstride);
                s1 += *(const f32x4*)(src + p*pstride + 4);
            }
        } else {
            for (int p = 0; p < nsplit; ++p) {
                s0 += *(const f32x4*)(src + p*pstride);
                s1 += *(const f32x4*)(src + p*pstride + 4);
            }
        }
    }
    {
        const int bl = t127 >> 3;            // batch-within-slab (row/64)
        const int i0 = (t127 & 7) * 8;       // first c_in of the 8-run
        union { __bf16 h[8]; uint4 u; } cv;
        cv.h[0]=(__bf16)s0[0]; cv.h[1]=(__bf16)s0[1];
        cv.h[2]=(__bf16)s0[2]; cv.h[3]=(__bf16)s0[3];
        cv.h[4]=(__bf16)s1[0]; cv.h[5]=(__bf16)s1[1];
        cv.h[6]=(__bf16)s1[2]; cv.h[7]=(__bf16)s1[3];
        *(uint4*)(at + bl*256 + ((((c*64 + i0) >> 3) ^ bl) << 4)) = cv.u;
    }
    __syncthreads();

    bf16x8 a[4];
    #pragma unroll
    for (int ks = 0; ks < 4; ++ks)
        a[ks] = *(const bf16x8*)(at + l15*256 + (((ks*4 + kg) ^ l15) << 4));

    f32x4 accR = {}, accI = {};
    #pragma unroll
    for (int ks = 0; ks < 4; ++ks) {
        bf16x8 b0 = *(const bf16x8*)(Wtf + (size_t)(((k*2+0)*4+ks)*4+ot)*512 + lane*8);
        accR = __builtin_amdgcn_mfma_f32_16x16x32_bf16(a[ks], b0, accR, 0, 0, 0);
    }
    #pragma unroll
    for (int ks = 0; ks < 4; ++ks) {
        bf16x8 b1 = *(const bf16x8*)(Wtf + (size_t)(((k*2+1)*4+ks)*4+ot)*512 + lane*8);
        accI = __builtin_amdgcn_mfma_f32_16x16x32_bf16(a[ks], b1, accI, 0, 0, 0);
    }
    #pragma unroll
    for (int rr = 0; rr < 4; ++rr) {
        int bg = bq*16 + kg*4 + rr;
        size_t r = (size_t)bg * CO + ot*16 + l15;
        ushort2 pk;
        pk.x = __builtin_bit_cast(unsigned short, (__bf16)accR[rr]);
        pk.y = __builtin_bit_cast(unsigned short, (__bf16)accI[rr]);
        *(ushort2*)(M2 + r * NFJ + 2 * k) = pk;
    }
}

// Kernel 3: IDFT GEMM. Block = 128 r x 128 n, 512 thr (waves 4x2),
// LDS 32 KB -> 4 blocks/CU (100% occupancy). Grid 2048.
__global__ __launch_bounds__(512) void sc_idft(const __bf16* __restrict__ M2,
                                               const __bf16* __restrict__ Ginv,
                                               float* __restrict__ out) {
    __shared__ __align__(16) char gls[32768];  // [128 n][128 j] bf16, swz ^(n&15)
    const int tid = threadIdx.x;
    const int w = tid >> 6, lane = tid & 63;
    const int l15 = lane & 15, kg = lane >> 4;
    const int wm = w >> 1;            // 0..3 -> 32 rows
    const int wn = w & 1;             // 0..1 -> 64 n
    const int r0 = (blockIdx.x >> 6) * 128;
    const int n0 = (blockIdx.x & 63) * 128;

    #pragma unroll
    for (int s = 0; s < 4; ++s) {
        int cc = s * 512 + tid;
        GLOAD_LDS16(Ginv + (size_t)n0 * NFJ + cc * 8, gls + cc * 16);
    }

    bf16x8 af[2][4];
    #pragma unroll
    for (int mt = 0; mt < 2; ++mt)
        #pragma unroll
        for (int ks = 0; ks < 4; ++ks)
            af[mt][ks] = *(const bf16x8*)(M2 + (size_t)(r0 + wm*32 + mt*16 + l15) * NFJ +
                                          ks*32 + kg*8);
    __syncthreads();

    f32x4 acc[2][4] = {};
    #pragma unroll
    for (int nt = 0; nt < 4; ++nt) {
        int row = wn*64 + nt*16 + l15;
        bf16x8 bfr[4];
        #pragma unroll
        for (int ks = 0; ks < 4; ++ks)
            bfr[ks] = *(const bf16x8*)(gls + row * 256 + (((ks*4 + kg) ^ (row & 15)) << 4));
        #pragma unroll
        for (int mt = 0; mt < 2; ++mt)
            #pragma unroll
            for (int ks = 0; ks < 4; ++ks)
                acc[mt][nt] = __builtin_amdgcn_mfma_f32_16x16x32_bf16(
                    af[mt][ks], bfr[ks], acc[mt][nt], 0, 0, 0);
    }
    #pragma unroll
    for (int mt = 0; mt < 2; ++mt)
        #pragma unroll
        for (int nt = 0; nt < 4; ++nt)
            #pragma unroll
            for (int rr = 0; rr < 4; ++rr)
                out[(size_t)(r0 + wm*32 + mt*16 + kg*4 + rr) * NG +
                    n0 + wn*64 + nt*16 + l15] = acc[mt][nt][rr];
}

extern "C" void kernel_launch(void* const* d_in, const int* in_sizes, int n_in,
                              void* d_out, int out_size, void* d_ws, size_t ws_size,
                              hipStream_t stream) {
    const float* lhss = (const float*)d_in[0];
    const float* w_real = (const float*)d_in[1];
    const float* w_imag = (const float*)d_in[2];
    float* out = (float*)d_out;

    char* ws = (char*)d_ws;
    __bf16* Ft_sw   = (__bf16*)ws;                     // 2 MB
    __bf16* Ginv_sw = (__bf16*)(ws + (2u << 20));      // 2 MB
    __bf16* M2      = (__bf16*)(ws + (6u << 20));      // 1 MB
    __bf16* Wtf     = (__bf16*)(ws + (7u << 20));      // 2 MB
    float*  XFp     = (float*) (ws + (9u << 20));      // split*2 MB

    int split;
    if      (ws_size >= (25u << 20)) split = 8;
    else if (ws_size >= (17u << 20)) split = 4;
    else if (ws_size >= (13u << 20)) split = 2;
    else                             split = 1;
    int nsteps = 128 / split;

    sc_prep<<<8256, 256, 0, stream>>>(w_real, w_imag, Ft_sw, Ginv_sw, Wtf);
    sc_dft<<<64 * split, 256, 0, stream>>>(lhss, Ft_sw, XFp, nsteps);
    sc_mix<<<256, 256, 0, stream>>>(XFp, Wtf, M2, split);
    sc_idft<<<2048, 512, 0, stream>>>(M2, Ginv_sw, out);
}